// Round 7
// baseline (106.856 us; speedup 1.0000x reference)
//
#include <hip/hip_runtime.h>

#define D_MODEL 256
#define TX 512
#define TM 512

__device__ __forceinline__ float fexp2(float x) { return __builtin_amdgcn_exp2f(x); }
__device__ __forceinline__ float frcp(float x)  { return __builtin_amdgcn_rcpf(x); }

// Two NT-GEMMs in one launch; epilogues write exp2(2log2e * value):
//  z=0: E1 [2048][256] = exp2(c*(x · w1^T + b1))           row-major
//  z=1: E2p packed     = exp2(c*(w2 · mem^T))  at [(d>>2)*8192 + gm*4 + (d&3)]
// Grid (32, 4, 2), block 256.
__global__ __launch_bounds__(256) void gemm_exp2(
    const float* __restrict__ x,   const float* __restrict__ mem,
    const float* __restrict__ w1,  const float* __restrict__ b1,
    const float* __restrict__ w2,
    float* __restrict__ E1, float* __restrict__ E2p)
{
    const float C_SCALE = 2.8853900817779268f; // 2*log2(e)
    const float* A; const float* W;
    int r0, n0;
    if (blockIdx.z == 0) { A = x;  W = w1; r0 = blockIdx.x * 64; n0 = blockIdx.y * 64; }
    else                 { A = w2; W = mem; r0 = blockIdx.y * 64; n0 = blockIdx.x * 64; }

    __shared__ float As[16][68];
    __shared__ float Ws[16][68];
    const int tid = threadIdx.x;
    const int tx = tid & 15, ty = tid >> 4;
    const int rl = tid >> 2, g = tid & 3;
    float acc[4][4] = {};
    const float* Ap = A + (size_t)(r0 + rl) * 256 + g * 4;
    const float* Wp = W + (size_t)(n0 + rl) * 256 + g * 4;
    for (int k0 = 0; k0 < 256; k0 += 16) {
        float4 a4 = *(const float4*)(Ap + k0);
        float4 w4 = *(const float4*)(Wp + k0);
        __syncthreads();
        As[g*4+0][rl] = a4.x; As[g*4+1][rl] = a4.y;
        As[g*4+2][rl] = a4.z; As[g*4+3][rl] = a4.w;
        Ws[g*4+0][rl] = w4.x; Ws[g*4+1][rl] = w4.y;
        Ws[g*4+2][rl] = w4.z; Ws[g*4+3][rl] = w4.w;
        __syncthreads();
        #pragma unroll
        for (int kk = 0; kk < 16; ++kk) {
            float4 av = *(const float4*)&As[kk][ty*4];
            float4 wv = *(const float4*)&Ws[kk][tx*4];
            float a_[4] = {av.x, av.y, av.z, av.w};
            float w_[4] = {wv.x, wv.y, wv.z, wv.w};
            #pragma unroll
            for (int i = 0; i < 4; ++i)
                #pragma unroll
                for (int j = 0; j < 4; ++j)
                    acc[i][j] = fmaf(a_[i], w_[j], acc[i][j]);
        }
    }
    if (blockIdx.z == 0) {
        #pragma unroll
        for (int i = 0; i < 4; ++i) {
            const int r = r0 + ty*4 + i;
            #pragma unroll
            for (int j = 0; j < 4; ++j) {
                const int n = n0 + tx*4 + j;
                E1[(size_t)r*256 + n] = fexp2(C_SCALE * (acc[i][j] + b1[n]));
            }
        }
    } else {
        #pragma unroll
        for (int i = 0; i < 4; ++i) {
            const int r = r0 + ty*4 + i;   // d index
            #pragma unroll
            for (int j = 0; j < 4; ++j) {
                const int n = n0 + tx*4 + j;  // gm index
                E2p[(size_t)(r >> 2)*8192 + (size_t)n*4 + (r & 3)] = fexp2(C_SCALE * acc[i][j]);
            }
        }
    }
}

// Fused: S = Wsum - 2*sum_d w[d]/(1+E1*E2), mask, softmax, single-pass PV.
// Grid 256, block 1024 (16 waves). Block owns 8 x-rows.
// Thread t: m = t&511, d-half = t>>9 (128 d each). E1/wst read via scalar loads.
__global__ __launch_bounds__(1024) void fused_tanh_attn(
    const float* __restrict__ E1,     // [B*TX, D]
    const float* __restrict__ E2p,    // packed [(d>>2)][gm][4]
    const float* __restrict__ memory, // [B, TM, D]
    const int*   __restrict__ mask,   // [B, TM]
    const float* __restrict__ wst,    // [D]
    float* __restrict__ out,          // [B*TX, D]
    float* __restrict__ Sout)         // [B*TX, TM]
{
    const float LOG2E = 1.4426950408889634f;
    const int t = threadIdx.x;
    // XCD-locality remap: dispatch XCD = blockIdx&7; give each XCD blocks of one batch.
    const int xcd  = (int)(blockIdx.x & 7);
    const int slot = (int)(blockIdx.x >> 3);          // 0..31
    const int b    = xcd >> 1;                        // batch 0..3 (2 XCDs per batch)
    const int widx = (xcd & 1) * 32 + slot;           // 0..63 within batch
    const int x0   = widx * 8;
    const int wave = t >> 6, lane = t & 63;
    const int m  = t & 511;
    const int dh = t >> 9;                            // 0 or 1

    __shared__ float P[8][TM];        // 16 KB
    __shared__ float mneg[TM];        // 2 KB
    __shared__ float oacc[8][D_MODEL];// 8 KB
    __shared__ float wpart[4];

    if (t < 512) mneg[t] = mask[b*TM + t] ? 0.f : -__builtin_inff();
    // zero PV accumulator (1024 threads x 8B = 8KB)
    ((float2*)oacc)[t] = float2{0.f, 0.f};

    // Wsum = sum(wst): waves 0..3
    if (wave < 4) {
        float s = wst[wave * 64 + lane];
        #pragma unroll
        for (int off = 32; off > 0; off >>= 1) s += __shfl_xor(s, off);
        if (lane == 0) wpart[wave] = s;
    }

    // ---- main loop: 32 groups of 4 d in this thread's d-half ----
    const int g0 = dh * 32;
    const float* e2ptr  = E2p + ((size_t)b * TM + m) * 4;
    const float* e1base = E1 + ((size_t)b * TX + x0) * D_MODEL;  // 8 rows, uniform
    float4 e2 = *(const float4*)(e2ptr + (size_t)g0 * 8192);

    __syncthreads();
    const float Wsum = wpart[0] + wpart[1] + wpart[2] + wpart[3];

    float acc[8] = {};
    for (int gi = 0; gi < 32; ++gi) {
        const int g = g0 + gi;
        float4 e2n = e2;
        if (gi < 31) e2n = *(const float4*)(e2ptr + (size_t)(g + 1) * 8192);
        const float4 w4 = *(const float4*)(wst + g * 4);          // s_load
        #pragma unroll
        for (int r = 0; r < 8; ++r) {
            const float4 a = *(const float4*)(e1base + r * D_MODEL + g * 4);  // s_load
            acc[r] = fmaf(w4.x, frcp(fmaf(a.x, e2.x, 1.f)), acc[r]);
            acc[r] = fmaf(w4.y, frcp(fmaf(a.y, e2.y, 1.f)), acc[r]);
            acc[r] = fmaf(w4.z, frcp(fmaf(a.z, e2.z, 1.f)), acc[r]);
            acc[r] = fmaf(w4.w, frcp(fmaf(a.w, e2.w, 1.f)), acc[r]);
        }
        e2 = e2n;
    }

    // ---- combine d-halves, apply Wsum/mask ----
    if (dh == 0) {
        #pragma unroll
        for (int r = 0; r < 8; ++r) P[r][m] = acc[r];
    }
    __syncthreads();
    if (dh == 1) {
        const float mn = mneg[m];
        #pragma unroll
        for (int r = 0; r < 8; ++r)
            P[r][m] = Wsum - 2.f * (P[r][m] + acc[r]) + mn;
    }
    __syncthreads();

    // ---- softmax: waves 0..7 -> rows 0..7 (8 values per lane) ----
    if (wave < 8) {
        const int xx = wave;
        float4 u0 = *(const float4*)&P[xx][lane * 8];
        float4 u1 = *(const float4*)&P[xx][lane * 8 + 4];
        float v[8] = {u0.x,u0.y,u0.z,u0.w,u1.x,u1.y,u1.z,u1.w};
        float mx = v[0];
        #pragma unroll
        for (int q = 1; q < 8; ++q) mx = fmaxf(mx, v[q]);
        #pragma unroll
        for (int off = 32; off > 0; off >>= 1) mx = fmaxf(mx, __shfl_xor(mx, off));
        float e[8];
        float sum = 0.f;
        #pragma unroll
        for (int q = 0; q < 8; ++q) { e[q] = fexp2((v[q] - mx) * LOG2E); sum += e[q]; }
        #pragma unroll
        for (int off = 32; off > 0; off >>= 1) sum += __shfl_xor(sum, off);
        const float inv = frcp(sum);
        float4 p0 = {e[0]*inv, e[1]*inv, e[2]*inv, e[3]*inv};
        float4 p1 = {e[4]*inv, e[5]*inv, e[6]*inv, e[7]*inv};
        *(float4*)&P[xx][lane*8]   = p0;
        *(float4*)&P[xx][lane*8+4] = p1;
        float* Sg = Sout + ((size_t)b*TX + x0 + xx) * TM + lane*8;
        *(float4*)Sg     = p0;
        *(float4*)(Sg+4) = p1;
    }
    __syncthreads();

    // ---- PV single-pass: wave owns 32 m; memory read once per block ----
    {
        const int m0 = wave * 32;
        const float* memp = memory + ((size_t)b * TM + m0) * D_MODEL + lane * 4;
        float4 o[8] = {};
        for (int mm4 = 0; mm4 < 8; ++mm4) {
            float4 p4[8];
            #pragma unroll
            for (int r = 0; r < 8; ++r) p4[r] = *(const float4*)&P[r][m0 + mm4*4];
            #pragma unroll
            for (int j = 0; j < 4; ++j) {
                float4 mv = *(const float4*)(memp + (size_t)(mm4*4 + j) * D_MODEL);
                const float pj[8] = {p4[0].x, p4[1].x, p4[2].x, p4[3].x,
                                     p4[4].x, p4[5].x, p4[6].x, p4[7].x};
                // select component j of each p4[r]
                #pragma unroll
                for (int r = 0; r < 8; ++r) {
                    const float p = (j == 0) ? p4[r].x : (j == 1) ? p4[r].y : (j == 2) ? p4[r].z : p4[r].w;
                    o[r].x = fmaf(p, mv.x, o[r].x);
                    o[r].y = fmaf(p, mv.y, o[r].y);
                    o[r].z = fmaf(p, mv.z, o[r].z);
                    o[r].w = fmaf(p, mv.w, o[r].w);
                }
                (void)pj;
            }
        }
        #pragma unroll
        for (int r = 0; r < 8; ++r) {
            atomicAdd(&oacc[r][lane*4 + 0], o[r].x);
            atomicAdd(&oacc[r][lane*4 + 1], o[r].y);
            atomicAdd(&oacc[r][lane*4 + 2], o[r].z);
            atomicAdd(&oacc[r][lane*4 + 3], o[r].w);
        }
    }
    __syncthreads();

    // ---- write out: 2048 outputs, 2 per thread ----
    #pragma unroll
    for (int k = 0; k < 2; ++k) {
        const int idx = t + k * 1024;
        const int row = idx >> 8, d0 = idx & 255;
        out[((size_t)b*TX + x0 + row) * D_MODEL + d0] = oacc[row][d0];
    }
}

extern "C" void kernel_launch(void* const* d_in, const int* in_sizes, int n_in,
                              void* d_out, int out_size, void* d_ws, size_t ws_size,
                              hipStream_t stream) {
    const float* x    = (const float*)d_in[0];
    const float* mem  = (const float*)d_in[1];
    const int*   mask = (const int*)d_in[2];
    const float* w1   = (const float*)d_in[3];
    const float* b1   = (const float*)d_in[4];
    const float* w2   = (const float*)d_in[5];
    const float* wst  = (const float*)d_in[6];

    float* out  = (float*)d_out;                  // [4*512*256]
    float* Sout = out + 4 * 512 * 256;            // [4*512*512]
    float* E1   = (float*)d_ws;                   // 524288 floats (2 MB), [2048][256]
    float* E2p  = E1 + 4 * 512 * 256;             // 524288 floats (2 MB), packed

    dim3 gg(32, 4, 2);
    gemm_exp2<<<gg, 256, 0, stream>>>(x, mem, w1, b1, w2, E1, E2p);
    fused_tanh_attn<<<256, 1024, 0, stream>>>(E1, E2p, mem, mask, wst, out, Sout);
}

// Round 8
// 66.140 us; speedup vs baseline: 1.6156x; 1.6156x over previous
//
#include <hip/hip_runtime.h>

#define D_MODEL 256
#define TX 512
#define TM 512

__device__ __forceinline__ float fexp2(float x) { return __builtin_amdgcn_exp2f(x); }
__device__ __forceinline__ float frcp(float x)  { return __builtin_amdgcn_rcpf(x); }

// Two NT-GEMMs in one launch; epilogues write exp2(2log2e * value):
//  z=0: E1 [2048][256] = exp2(c*(x · w1^T + b1))           row-major
//  z=1: E2p packed     = exp2(c*(w2 · mem^T))  at [(d>>2)*8192 + gm*4 + (d&3)]
// Grid (32, 4, 2), block 256.
__global__ __launch_bounds__(256) void gemm_exp2(
    const float* __restrict__ x,   const float* __restrict__ mem,
    const float* __restrict__ w1,  const float* __restrict__ b1,
    const float* __restrict__ w2,
    float* __restrict__ E1, float* __restrict__ E2p)
{
    const float C_SCALE = 2.8853900817779268f; // 2*log2(e)
    const float* A; const float* W;
    int r0, n0;
    if (blockIdx.z == 0) { A = x;  W = w1; r0 = blockIdx.x * 64; n0 = blockIdx.y * 64; }
    else                 { A = w2; W = mem; r0 = blockIdx.y * 64; n0 = blockIdx.x * 64; }

    __shared__ float As[16][68];
    __shared__ float Ws[16][68];
    const int tid = threadIdx.x;
    const int tx = tid & 15, ty = tid >> 4;
    const int rl = tid >> 2, g = tid & 3;
    float acc[4][4] = {};
    const float* Ap = A + (size_t)(r0 + rl) * 256 + g * 4;
    const float* Wp = W + (size_t)(n0 + rl) * 256 + g * 4;
    for (int k0 = 0; k0 < 256; k0 += 16) {
        float4 a4 = *(const float4*)(Ap + k0);
        float4 w4 = *(const float4*)(Wp + k0);
        __syncthreads();
        As[g*4+0][rl] = a4.x; As[g*4+1][rl] = a4.y;
        As[g*4+2][rl] = a4.z; As[g*4+3][rl] = a4.w;
        Ws[g*4+0][rl] = w4.x; Ws[g*4+1][rl] = w4.y;
        Ws[g*4+2][rl] = w4.z; Ws[g*4+3][rl] = w4.w;
        __syncthreads();
        #pragma unroll
        for (int kk = 0; kk < 16; ++kk) {
            float4 av = *(const float4*)&As[kk][ty*4];
            float4 wv = *(const float4*)&Ws[kk][tx*4];
            float a_[4] = {av.x, av.y, av.z, av.w};
            float w_[4] = {wv.x, wv.y, wv.z, wv.w};
            #pragma unroll
            for (int i = 0; i < 4; ++i)
                #pragma unroll
                for (int j = 0; j < 4; ++j)
                    acc[i][j] = fmaf(a_[i], w_[j], acc[i][j]);
        }
    }
    if (blockIdx.z == 0) {
        #pragma unroll
        for (int i = 0; i < 4; ++i) {
            const int r = r0 + ty*4 + i;
            #pragma unroll
            for (int j = 0; j < 4; ++j) {
                const int n = n0 + tx*4 + j;
                E1[(size_t)r*256 + n] = fexp2(C_SCALE * (acc[i][j] + b1[n]));
            }
        }
    } else {
        #pragma unroll
        for (int i = 0; i < 4; ++i) {
            const int r = r0 + ty*4 + i;   // d index
            #pragma unroll
            for (int j = 0; j < 4; ++j) {
                const int n = n0 + tx*4 + j;  // gm index
                E2p[(size_t)(r >> 2)*8192 + (size_t)n*4 + (r & 3)] = fexp2(C_SCALE * acc[i][j]);
            }
        }
    }
}

// Fused: S = Wsum - 2*sum_d w[d]/(1+E1*E2), mask, softmax, single-pass PV.
// Grid 1024 (= B*TX/2), block 256 (4 waves). Block owns 2 x-rows;
// thread t owns m = t and m = t+256.
__global__ __launch_bounds__(256) void fused_tanh_attn(
    const float* __restrict__ E1,     // [B*TX, D]
    const float* __restrict__ E2p,    // packed [(d>>2)][gm][4]
    const float* __restrict__ memory, // [B, TM, D]
    const int*   __restrict__ mask,   // [B, TM]
    const float* __restrict__ wst,    // [D]
    float* __restrict__ out,          // [B*TX, D]
    float* __restrict__ Sout)         // [B*TX, TM]
{
    const float LOG2E = 1.4426950408889634f;
    const int t = threadIdx.x;
    // XCD-aware bijective swizzle (1024 = 8*128): batch b -> 2 XCDs
    const int blk = (int)((blockIdx.x & 7) * 128 + (blockIdx.x >> 3));
    const int b = blk >> 8;                // 256 blocks per batch
    const int x0 = (blk & 255) * 2;
    const int wave = t >> 6, lane = t & 63;

    __shared__ float i1R[2][D_MODEL];       // 2 KB
    __shared__ float wsh[D_MODEL];          // 1 KB
    __shared__ float P[2][TM];              // 4 KB
    __shared__ float mneg[TM];              // 2 KB
    __shared__ float opart[2][4][D_MODEL];  // 8 KB
    __shared__ float wpart[4];

    // stage E1 rows, wst, mask
    {
        const float* i1g = E1 + ((size_t)b * TX + x0) * D_MODEL;
        const int row = t >> 7, col2 = (t & 127) * 2;
        float2 v = *(const float2*)(i1g + (size_t)row * D_MODEL + col2);
        *(float2*)&i1R[row][col2] = v;
    }
    wsh[t] = wst[t];
    mneg[t]       = mask[b*TM + t]       ? 0.f : -__builtin_inff();
    mneg[t + 256] = mask[b*TM + t + 256] ? 0.f : -__builtin_inff();

    // Wsum = sum(wst)
    {
        float s = wst[t];
        #pragma unroll
        for (int off = 32; off > 0; off >>= 1) s += __shfl_xor(s, off);
        if (lane == 0) wpart[wave] = s;
    }

    // first E2 group loads (both m streams)
    const float* e2ptrA = E2p + ((size_t)b * TM + t) * 4;
    const float* e2ptrB = e2ptrA + 1024;   // m + 256
    float4 e2a = *(const float4*)e2ptrA;
    float4 e2b = *(const float4*)e2ptrB;

    __syncthreads();
    const float Wsum = wpart[0] + wpart[1] + wpart[2] + wpart[3];

    // main loop: 64 groups of 4 d; 1-deep prefetch; rcp-based eval
    float accA0 = 0.f, accA1 = 0.f, accB0 = 0.f, accB1 = 0.f;
    #pragma unroll 2
    for (int gg = 0; gg < 64; ++gg) {
        float4 e2an = e2a, e2bn = e2b;
        if (gg < 63) {
            e2an = *(const float4*)(e2ptrA + (size_t)(gg + 1) * 8192);
            e2bn = *(const float4*)(e2ptrB + (size_t)(gg + 1) * 8192);
        }
        float4 a0 = *(const float4*)&i1R[0][gg * 4];
        float4 a1 = *(const float4*)&i1R[1][gg * 4];
        float4 w4 = *(const float4*)&wsh[gg * 4];
        accA0 = fmaf(w4.x, frcp(fmaf(a0.x, e2a.x, 1.f)), accA0);
        accA0 = fmaf(w4.y, frcp(fmaf(a0.y, e2a.y, 1.f)), accA0);
        accA0 = fmaf(w4.z, frcp(fmaf(a0.z, e2a.z, 1.f)), accA0);
        accA0 = fmaf(w4.w, frcp(fmaf(a0.w, e2a.w, 1.f)), accA0);
        accA1 = fmaf(w4.x, frcp(fmaf(a1.x, e2a.x, 1.f)), accA1);
        accA1 = fmaf(w4.y, frcp(fmaf(a1.y, e2a.y, 1.f)), accA1);
        accA1 = fmaf(w4.z, frcp(fmaf(a1.z, e2a.z, 1.f)), accA1);
        accA1 = fmaf(w4.w, frcp(fmaf(a1.w, e2a.w, 1.f)), accA1);
        accB0 = fmaf(w4.x, frcp(fmaf(a0.x, e2b.x, 1.f)), accB0);
        accB0 = fmaf(w4.y, frcp(fmaf(a0.y, e2b.y, 1.f)), accB0);
        accB0 = fmaf(w4.z, frcp(fmaf(a0.z, e2b.z, 1.f)), accB0);
        accB0 = fmaf(w4.w, frcp(fmaf(a0.w, e2b.w, 1.f)), accB0);
        accB1 = fmaf(w4.x, frcp(fmaf(a1.x, e2b.x, 1.f)), accB1);
        accB1 = fmaf(w4.y, frcp(fmaf(a1.y, e2b.y, 1.f)), accB1);
        accB1 = fmaf(w4.z, frcp(fmaf(a1.z, e2b.z, 1.f)), accB1);
        accB1 = fmaf(w4.w, frcp(fmaf(a1.w, e2b.w, 1.f)), accB1);
        e2a = e2an; e2b = e2bn;
    }

    // scores with mask
    {
        P[0][t]       = Wsum - 2.f * accA0 + mneg[t];
        P[1][t]       = Wsum - 2.f * accA1 + mneg[t];
        P[0][t + 256] = Wsum - 2.f * accB0 + mneg[t + 256];
        P[1][t + 256] = Wsum - 2.f * accB1 + mneg[t + 256];
    }
    __syncthreads();

    // softmax: wave 0 -> row 0, wave 1 -> row 1 (8 values per lane)
    if (wave < 2) {
        const int xx = wave;
        float4 u0 = *(const float4*)&P[xx][lane * 8];
        float4 u1 = *(const float4*)&P[xx][lane * 8 + 4];
        float v[8] = {u0.x,u0.y,u0.z,u0.w,u1.x,u1.y,u1.z,u1.w};
        float mx = v[0];
        #pragma unroll
        for (int q = 1; q < 8; ++q) mx = fmaxf(mx, v[q]);
        #pragma unroll
        for (int off = 32; off > 0; off >>= 1) mx = fmaxf(mx, __shfl_xor(mx, off));
        float e[8];
        float sum = 0.f;
        #pragma unroll
        for (int q = 0; q < 8; ++q) { e[q] = fexp2((v[q] - mx) * LOG2E); sum += e[q]; }
        #pragma unroll
        for (int off = 32; off > 0; off >>= 1) sum += __shfl_xor(sum, off);
        const float inv = frcp(sum);
        float4 p0 = {e[0]*inv, e[1]*inv, e[2]*inv, e[3]*inv};
        float4 p1 = {e[4]*inv, e[5]*inv, e[6]*inv, e[7]*inv};
        *(float4*)&P[xx][lane*8]   = p0;
        *(float4*)&P[xx][lane*8+4] = p1;
        float* Sg = Sout + ((size_t)b*TX + x0 + xx) * TM + lane*8;
        *(float4*)Sg     = p0;
        *(float4*)(Sg+4) = p1;
    }
    __syncthreads();

    // PV single-pass: wave w owns m-quarter [w*128, w*128+128); both rows per load.
    // Each memory element read exactly once per block.
    {
        const int m0 = wave * 128;
        const float* memp = memory + ((size_t)b * TM + m0) * D_MODEL + lane * 4;
        float4 o0 = {0,0,0,0}, o1 = {0,0,0,0};
        #pragma unroll 4
        for (int mm = 0; mm < 128; ++mm) {
            float4 mv = *(const float4*)(memp + (size_t)mm * D_MODEL);
            const float p0 = P[0][m0 + mm];
            const float p1 = P[1][m0 + mm];
            o0.x = fmaf(p0, mv.x, o0.x); o0.y = fmaf(p0, mv.y, o0.y);
            o0.z = fmaf(p0, mv.z, o0.z); o0.w = fmaf(p0, mv.w, o0.w);
            o1.x = fmaf(p1, mv.x, o1.x); o1.y = fmaf(p1, mv.y, o1.y);
            o1.z = fmaf(p1, mv.z, o1.z); o1.w = fmaf(p1, mv.w, o1.w);
        }
        *(float4*)&opart[0][wave][lane*4] = o0;
        *(float4*)&opart[1][wave][lane*4] = o1;
    }
    __syncthreads();

    // combine quarters: 512 outputs, 2 per thread
    {
        #pragma unroll
        for (int k = 0; k < 2; ++k) {
            const int idx = t + k * 256;
            const int row = idx >> 8, d0 = idx & 255;
            float s = opart[row][0][d0] + opart[row][1][d0]
                    + opart[row][2][d0] + opart[row][3][d0];
            out[((size_t)b*TX + x0 + row) * D_MODEL + d0] = s;
        }
    }
}

extern "C" void kernel_launch(void* const* d_in, const int* in_sizes, int n_in,
                              void* d_out, int out_size, void* d_ws, size_t ws_size,
                              hipStream_t stream) {
    const float* x    = (const float*)d_in[0];
    const float* mem  = (const float*)d_in[1];
    const int*   mask = (const int*)d_in[2];
    const float* w1   = (const float*)d_in[3];
    const float* b1   = (const float*)d_in[4];
    const float* w2   = (const float*)d_in[5];
    const float* wst  = (const float*)d_in[6];

    float* out  = (float*)d_out;                  // [4*512*256]
    float* Sout = out + 4 * 512 * 256;            // [4*512*512]
    float* E1   = (float*)d_ws;                   // 524288 floats (2 MB), [2048][256]
    float* E2p  = E1 + 4 * 512 * 256;             // 524288 floats (2 MB), packed

    dim3 gg(32, 4, 2);
    gemm_exp2<<<gg, 256, 0, stream>>>(x, mem, w1, b1, w2, E1, E2p);
    fused_tanh_attn<<<1024, 256, 0, stream>>>(E1, E2p, mem, mask, wst, out, Sout);
}